// Round 5
// baseline (542.123 us; speedup 1.0000x reference)
//
#include <hip/hip_runtime.h>
#include <math.h>

typedef __attribute__((ext_vector_type(8))) short short8;
typedef __attribute__((ext_vector_type(4))) float f32x4;

#define UNITS 512
#define DIN 128

// ws float offsets:
#define WS_COLSA  0        // 128 floats, colsum(A), atomic (zeroed)
#define WS_SCALE  512      // 512
#define WS_SHIFT  1024     // 512
#define WS_ESLOT  1536     // 512 entropy slots, atomic (zeroed)
#define WS_GF     2048     // 16384, G final (128x128)
#define WS_WHI    20480    // 65536 ushorts (32768 floats)
#define WS_WLO    53248    // 65536 ushorts
#define N_ESLOT   512
#define WS_ZERO_FLOATS 2048

#define GRAM_BLOCKS 512    // G partials: GRAM_BLOCKS x 16384 floats in d_out scratch

__device__ __forceinline__ unsigned short f2bf(float f) {
    unsigned u = __float_as_uint(f);
    unsigned r = (u + 0x7FFFu + ((u >> 16) & 1u)) >> 16;   // RNE
    return (unsigned short)r;
}
__device__ __forceinline__ float bf2f(unsigned short h) {
    return __uint_as_float(((unsigned)h) << 16);
}

// K0: pack W [128][512] fp32 -> fragment-major bf16 hi/lo.
// (k,n): c=k>>5, lane=((k>>3)&3)*16+(n&15), j=k&7, t=n>>4
__global__ void k0_packW(const float* __restrict__ W, unsigned short* __restrict__ Whi,
                         unsigned short* __restrict__ Wlo)
{
    int idx = blockIdx.x * 256 + threadIdx.x;   // 0..65535
    int k = idx >> 9, n = idx & 511;
    float v = W[idx];
    int c = k >> 5, j = k & 7, lane = ((k >> 3) & 3) * 16 + (n & 15), t = n >> 4;
    int dst = (((c * 32 + t) * 64 + lane) << 3) + j;
    unsigned short hi = f2bf(v);
    unsigned short lo = f2bf(v - bf2f(hi));
    Whi[dst] = hi;
    Wlo[dst] = lo;
}

// K1a: Gram partials G_b = A_b^T A_b (3-term split-bf16 MFMA) + colsum(A).
// Block = 4 waves; wave w owns G tile-rows {2w,2w+1} x 8 tile-cols.
// Plain stores of the 128x128 partial into Gpart + blockIdx*16384 (NO atomics).
__global__ __launch_bounds__(256) void k1a_gram(const float* __restrict__ A,
                                                float* __restrict__ Gpart,
                                                float* __restrict__ ws, int Brows)
{
    __shared__ float As[32][133];
    __shared__ float s_lds[128];
    const int t = threadIdx.x;
    const int wave = t >> 6, lane = t & 63, lg = lane >> 4, lm = lane & 15;
    const int rowsPerBlk = Brows / GRAM_BLOCKS;   // 256
    const int r0 = blockIdx.x * rowsPerBlk;

    if (t < 128) s_lds[t] = 0.f;
    float s_part[4] = {0.f, 0.f, 0.f, 0.f};

    f32x4 acc[16];
#pragma unroll
    for (int i = 0; i < 16; ++i) acc[i] = (f32x4){0.f, 0.f, 0.f, 0.f};

    for (int kk = 0; kk < rowsPerBlk; kk += 32) {
        __syncthreads();
#pragma unroll
        for (int i = 0; i < 4; ++i) {
            int fi = t + i * 256;
            int row = fi >> 5, c4 = (fi & 31) * 4;
            float4 v = *(const float4*)(A + (size_t)(r0 + kk + row) * DIN + c4);
            *(float4*)&As[row][c4] = v;
            s_part[0] += v.x; s_part[1] += v.y; s_part[2] += v.z; s_part[3] += v.w;
        }
        __syncthreads();
        // 8 fragments: frag[f] = cols f*16+lm, k = lg*8+j (valid as A- and B-operand)
        short8 fh[8], fl[8];
#pragma unroll
        for (int f = 0; f < 8; ++f) {
#pragma unroll
            for (int j = 0; j < 8; ++j) {
                float v = As[lg * 8 + j][f * 16 + lm];
                unsigned short h = f2bf(v);
                fh[f][j] = (short)h;
                fl[f][j] = (short)f2bf(v - bf2f(h));
            }
        }
#pragma unroll
        for (int a2 = 0; a2 < 2; ++a2) {
            short8 ah = fh[2 * wave + a2], al = fl[2 * wave + a2];
#pragma unroll
            for (int tj = 0; tj < 8; ++tj) {
                acc[a2 * 8 + tj] = __builtin_amdgcn_mfma_f32_16x16x32_bf16(al, fh[tj], acc[a2 * 8 + tj], 0, 0, 0);
                acc[a2 * 8 + tj] = __builtin_amdgcn_mfma_f32_16x16x32_bf16(ah, fl[tj], acc[a2 * 8 + tj], 0, 0, 0);
                acc[a2 * 8 + tj] = __builtin_amdgcn_mfma_f32_16x16x32_bf16(ah, fh[tj], acc[a2 * 8 + tj], 0, 0, 0);
            }
        }
    }

    // colsum(A): LDS combine then global atomics (trivial volume)
#pragma unroll
    for (int j = 0; j < 4; ++j) atomicAdd(&s_lds[(t & 31) * 4 + j], s_part[j]);
    __syncthreads();
    if (t < 128) atomicAdd(ws + WS_COLSA + t, s_lds[t]);

    // G partial -> plain stores (disjoint per block)
    float* Gs = Gpart + (size_t)blockIdx.x * 16384;
#pragma unroll
    for (int a2 = 0; a2 < 2; ++a2) {
#pragma unroll
        for (int tj = 0; tj < 8; ++tj) {
#pragma unroll
            for (int g = 0; g < 4; ++g) {
                int gi = (2 * wave + a2) * 16 + lg * 4 + g;
                int gj = tj * 16 + lm;
                Gs[gi * 128 + gj] = acc[a2 * 8 + tj][g];
            }
        }
    }
}

// K1b: reduce GRAM_BLOCKS partials -> G final in ws
__global__ __launch_bounds__(256) void k1b_sumG(const float* __restrict__ Gpart,
                                                float* __restrict__ ws)
{
    int i = blockIdx.x * 256 + threadIdx.x;   // 0..16383
    float v = 0.f;
#pragma unroll 8
    for (int s = 0; s < GRAM_BLOCKS; ++s) v += Gpart[(size_t)s * 16384 + i];
    ws[WS_GF + i] = v;
}

// K2: per-column BN stats from Gram: mean = (colsum(A).w)/N, sumsq = w^T G w.
__global__ __launch_bounds__(128) void k2_finalize(
    const float* __restrict__ W, const float* __restrict__ gamma,
    const float* __restrict__ beta, float* __restrict__ ws, int Brows)
{
    __shared__ float wcol[128];
    __shared__ float red[4];
    const int t = threadIdx.x, n = blockIdx.x;
    wcol[t] = W[(size_t)t * UNITS + n];
    __syncthreads();
    const float* GF = ws + WS_GF;
    float q = 0.f;
#pragma unroll 8
    for (int i = 0; i < 128; ++i) q += GF[i * 128 + t] * wcol[i];   // symmetric G
    q *= wcol[t];
    float mp = ws[WS_COLSA + t] * wcol[t];
#pragma unroll
    for (int off = 32; off; off >>= 1) {
        q  += __shfl_xor(q, off, 64);
        mp += __shfl_xor(mp, off, 64);
    }
    if ((t & 63) == 0) { red[(t >> 6) * 2] = q; red[(t >> 6) * 2 + 1] = mp; }
    __syncthreads();
    if (t == 0) {
        float sumsq = red[0] + red[2], ssum = red[1] + red[3];
        float invB = 1.0f / (float)Brows;
        float mean = ssum * invB;
        float var  = sumsq * invB - mean * mean;
        float rstd = rsqrtf(var + 1e-3f);
        float sc   = rstd * gamma[n];
        ws[WS_SCALE + n] = sc;
        ws[WS_SHIFT + n] = beta[n] - mean * sc;
    }
}

// K3: fused GEMM (split-bf16 MFMA) + BN + LDS row-transpose + PER-WAVE Newton
// sparsemax + mask write + entropy. Block = 512 thr, 32 rows.
__global__ __launch_bounds__(512) void k3_fused(
    const float* __restrict__ A, const unsigned short* __restrict__ Whi,
    const unsigned short* __restrict__ Wlo, const float* __restrict__ prior,
    float* __restrict__ out, float* __restrict__ ws)
{
    __shared__ float zbuf[32][516];   // stride 516 -> 2-way bank aliasing (free)
    __shared__ float lds_e[8];

    const int tid = threadIdx.x;
    const int wave = tid >> 6, lane = tid & 63, lg = lane >> 4, lm = lane & 15;
    const int rs = wave >> 2;          // row stripe 0/1
    const int cw = wave & 3;           // col wave: cols [cw*128, +128)
    const int r0 = blockIdx.x * 32 + rs * 16;

    // A fragments (16 rows, full K=128), split hi/lo
    short8 ahi[4], alo[4];
    const float* arow = A + (size_t)(r0 + lm) * DIN + lg * 8;
#pragma unroll
    for (int c = 0; c < 4; ++c) {
        float4 f0 = *(const float4*)(arow + c * 32);
        float4 f1 = *(const float4*)(arow + c * 32 + 4);
        float fv[8] = {f0.x, f0.y, f0.z, f0.w, f1.x, f1.y, f1.z, f1.w};
#pragma unroll
        for (int j = 0; j < 8; ++j) {
            unsigned short h = f2bf(fv[j]);
            ahi[c][j] = (short)h;
            alo[c][j] = (short)f2bf(fv[j] - bf2f(h));
        }
    }

    f32x4 acc[8];
#pragma unroll
    for (int i = 0; i < 8; ++i) acc[i] = (f32x4){0.f, 0.f, 0.f, 0.f};

#pragma unroll
    for (int c = 0; c < 4; ++c) {
        const short8* bh = (const short8*)Whi + (c * 32 + cw * 8) * 64 + lane;
        const short8* bl = (const short8*)Wlo + (c * 32 + cw * 8) * 64 + lane;
#pragma unroll
        for (int t8 = 0; t8 < 8; ++t8) {
            short8 h = bh[t8 * 64];
            short8 l = bl[t8 * 64];
            acc[t8] = __builtin_amdgcn_mfma_f32_16x16x32_bf16(alo[c], h, acc[t8], 0, 0, 0);
            acc[t8] = __builtin_amdgcn_mfma_f32_16x16x32_bf16(ahi[c], l, acc[t8], 0, 0, 0);
            acc[t8] = __builtin_amdgcn_mfma_f32_16x16x32_bf16(ahi[c], h, acc[t8], 0, 0, 0);
        }
    }

    // BN + prior, then transpose into LDS: zbuf[row][col]
    const float* prow = prior + (size_t)(r0 + lg * 4) * UNITS + cw * 128 + lm;
#pragma unroll
    for (int t8 = 0; t8 < 8; ++t8) {
        int col = cw * 128 + t8 * 16 + lm;
        float sc = ws[WS_SCALE + col];
        float sh = ws[WS_SHIFT + col];
#pragma unroll
        for (int g = 0; g < 4; ++g) {
            float p = prow[(size_t)g * UNITS + t8 * 16];
            float z = p * fmaf(acc[t8][g], sc, sh);
            zbuf[rs * 16 + lg * 4 + g][col] = z;
        }
    }
    __syncthreads();

    // Per-wave sparsemax: wave handles block-rows [wave*4, wave*4+4)
    float ent = 0.f;
#pragma unroll
    for (int rr = 0; rr < 4; ++rr) {
        const int row = wave * 4 + rr;
        float z[8];
#pragma unroll
        for (int e = 0; e < 8; ++e) z[e] = zbuf[row][lane + e * 64];

        float m = z[0];
#pragma unroll
        for (int e = 1; e < 8; ++e) m = fmaxf(m, z[e]);
#pragma unroll
        for (int off = 32; off; off >>= 1) m = fmaxf(m, __shfl_xor(m, off, 64));

        // Newton on f(tau)=sum(relu(z-tau))-1: monotone tau, exact fixed point,
        // wave-uniform early exit (no barriers).
        float tau = m - 1.0f;
        for (int it = 0; it < 24; ++it) {
            float S = 0.f, K = 0.f;
#pragma unroll
            for (int e = 0; e < 8; ++e) {
                if (z[e] > tau) { S += z[e]; K += 1.f; }
            }
#pragma unroll
            for (int off = 32; off; off >>= 1) {
                S += __shfl_xor(S, off, 64);
                K += __shfl_xor(K, off, 64);
            }
            if (K < 0.5f) break;
            float nt = (S - 1.0f) / K;
            if (!(nt > tau)) break;
            tau = nt;
        }

        float* orow = out + (size_t)(blockIdx.x * 32 + row) * UNITS + lane;
#pragma unroll
        for (int e = 0; e < 8; ++e) {
            float v = fmaxf(z[e] - tau, 0.f);
            orow[e * 64] = v;
            ent -= v * __logf(v + 1e-15f);
        }
    }

#pragma unroll
    for (int off = 32; off; off >>= 1) ent += __shfl_xor(ent, off, 64);
    if (lane == 0) lds_e[wave] = ent;
    __syncthreads();
    if (tid == 0) {
        float tot = 0.f;
#pragma unroll
        for (int w = 0; w < 8; ++w) tot += lds_e[w];
        atomicAdd(&ws[WS_ESLOT + (blockIdx.x & (N_ESLOT - 1))], tot);
    }
}

// K4: reduce entropy slots -> scalar loss
__global__ void k4_loss(const float* __restrict__ ws, float* __restrict__ out_loss,
                        int Brows)
{
    __shared__ float sh[512];
    int t = threadIdx.x;
    sh[t] = ws[WS_ESLOT + t];
    __syncthreads();
    for (int s = 256; s > 0; s >>= 1) {
        if (t < s) sh[t] += sh[t + s];
        __syncthreads();
    }
    if (t == 0) out_loss[0] = 1e-3f * (sh[0] / (float)Brows) * (1.0f / 3.0f);
}

extern "C" void kernel_launch(void* const* d_in, const int* in_sizes, int n_in,
                              void* d_out, int out_size, void* d_ws, size_t ws_size,
                              hipStream_t stream)
{
    const float* inputs = (const float*)d_in[0];
    const float* prior  = (const float*)d_in[1];
    const float* Wm     = (const float*)d_in[2];
    const float* gamma  = (const float*)d_in[3];
    const float* beta   = (const float*)d_in[4];
    float* out = (float*)d_out;
    float* ws  = (float*)d_ws;
    unsigned short* Whi = (unsigned short*)(ws + WS_WHI);
    unsigned short* Wlo = (unsigned short*)(ws + WS_WLO);
    const int Brows = in_sizes[1] / UNITS;   // 131072

    // d_out doubles as Gram-partial scratch (33.5 MB) before k3 overwrites it.
    float* Gpart = out;

    hipMemsetAsync(ws, 0, WS_ZERO_FLOATS * sizeof(float), stream);

    k0_packW<<<256, 256, 0, stream>>>(Wm, Whi, Wlo);
    k1a_gram<<<GRAM_BLOCKS, 256, 0, stream>>>(inputs, Gpart, ws, Brows);
    k1b_sumG<<<64, 256, 0, stream>>>(Gpart, ws);
    k2_finalize<<<UNITS, 128, 0, stream>>>(Wm, gamma, beta, ws, Brows);
    k3_fused<<<Brows / 32, 512, 0, stream>>>(inputs, Whi, Wlo, prior, out, ws);
    k4_loss<<<1, N_ESLOT, 0, stream>>>(ws, out + (size_t)Brows * UNITS, Brows);
}

// Round 6
// 313.299 us; speedup vs baseline: 1.7304x; 1.7304x over previous
//
#include <hip/hip_runtime.h>
#include <math.h>

typedef __attribute__((ext_vector_type(8))) short short8;
typedef __attribute__((ext_vector_type(4))) float f32x4;

#define UNITS 512
#define DIN 128

// ws float offsets:
#define WS_COLSA  0        // 8 slots x 128, colsum(A), atomic (zeroed)
#define WS_SCALE  1024     // 512
#define WS_SHIFT  1536     // 512
#define WS_ESLOT  2048     // 512 entropy slots, atomic (zeroed)
#define WS_GF     2560     // 16384, G final (128x128)
#define WS_WHI    19456    // 65536 ushorts (32768 floats)
#define WS_WLO    52224    // 65536 ushorts
#define N_ESLOT   512
#define WS_ZERO_FLOATS 2560

#define GRAM_BLOCKS 512    // G partials: GRAM_BLOCKS x 16384 floats in d_out scratch

__device__ __forceinline__ unsigned short f2bf(float f) {
    unsigned u = __float_as_uint(f);
    unsigned r = (u + 0x7FFFu + ((u >> 16) & 1u)) >> 16;   // RNE
    return (unsigned short)r;
}
__device__ __forceinline__ float bf2f(unsigned short h) {
    return __uint_as_float(((unsigned)h) << 16);
}

// K0: pack W [128][512] fp32 -> fragment-major bf16 hi/lo (RNE, runs once).
// (k,n): c=k>>5, lane=((k>>3)&3)*16+(n&15), j=k&7, t=n>>4
__global__ void k0_packW(const float* __restrict__ W, unsigned short* __restrict__ Whi,
                         unsigned short* __restrict__ Wlo)
{
    int idx = blockIdx.x * 256 + threadIdx.x;   // 0..65535
    int k = idx >> 9, n = idx & 511;
    float v = W[idx];
    int c = k >> 5, j = k & 7, lane = ((k >> 3) & 3) * 16 + (n & 15), t = n >> 4;
    int dst = (((c * 32 + t) * 64 + lane) << 3) + j;
    unsigned short hi = f2bf(v);
    unsigned short lo = f2bf(v - bf2f(hi));
    Whi[dst] = hi;
    Wlo[dst] = lo;
}

// K1a: Gram partials G_b = A_b^T A_b (3-term split-bf16 MFMA) + colsum(A).
// Block = 4 waves; wave w owns G tile-rows {2w,2w+1} x 8 tile-cols.
// NOTE: no runtime-indexed register arrays (rule #20) — the wave's A-operand
// fragments are NAMED regs rebuilt from LDS (runtime wave only in the address).
__global__ __launch_bounds__(256) void k1a_gram(const float* __restrict__ A,
                                                float* __restrict__ Gpart,
                                                float* __restrict__ ws, int Brows)
{
    __shared__ float As[32][133];
    __shared__ float s_lds[128];
    const int t = threadIdx.x;
    const int wave = t >> 6, lane = t & 63, lg = lane >> 4, lm = lane & 15;
    const int rowsPerBlk = Brows / GRAM_BLOCKS;   // 256
    const int r0 = blockIdx.x * rowsPerBlk;

    if (t < 128) s_lds[t] = 0.f;
    float s_part[4] = {0.f, 0.f, 0.f, 0.f};

    f32x4 acc[16];
#pragma unroll
    for (int i = 0; i < 16; ++i) acc[i] = (f32x4){0.f, 0.f, 0.f, 0.f};

    for (int kk = 0; kk < rowsPerBlk; kk += 32) {
        __syncthreads();
#pragma unroll
        for (int i = 0; i < 4; ++i) {
            int fi = t + i * 256;
            int row = fi >> 5, c4 = (fi & 31) * 4;
            float4 v = *(const float4*)(A + (size_t)(r0 + kk + row) * DIN + c4);
            *(float4*)&As[row][c4] = v;
            s_part[0] += v.x; s_part[1] += v.y; s_part[2] += v.z; s_part[3] += v.w;
        }
        __syncthreads();

        // B fragments (all 8 tile-cols), compile-time indexed only.
        // Truncation split: hi = top16(v); lo = top16(v - hi_f).
        short8 fh[8], fl[8];
#pragma unroll
        for (int f = 0; f < 8; ++f) {
#pragma unroll
            for (int j = 0; j < 8; ++j) {
                float v = As[lg * 8 + j][f * 16 + lm];
                unsigned uv = __float_as_uint(v);
                float lo = v - __uint_as_float(uv & 0xFFFF0000u);
                fh[f][j] = (short)(uv >> 16);
                fl[f][j] = (short)(__float_as_uint(lo) >> 16);
            }
        }
        // A-operand fragments for THIS wave (tile-rows 2w, 2w+1): named regs.
        short8 ah0, al0, ah1, al1;
#pragma unroll
        for (int j = 0; j < 8; ++j) {
            float v0 = As[lg * 8 + j][wave * 32 + lm];
            float v1 = As[lg * 8 + j][wave * 32 + 16 + lm];
            unsigned u0 = __float_as_uint(v0), u1 = __float_as_uint(v1);
            float l0 = v0 - __uint_as_float(u0 & 0xFFFF0000u);
            float l1 = v1 - __uint_as_float(u1 & 0xFFFF0000u);
            ah0[j] = (short)(u0 >> 16);
            al0[j] = (short)(__float_as_uint(l0) >> 16);
            ah1[j] = (short)(u1 >> 16);
            al1[j] = (short)(__float_as_uint(l1) >> 16);
        }

#pragma unroll
        for (int tj = 0; tj < 8; ++tj) {
            acc[tj]     = __builtin_amdgcn_mfma_f32_16x16x32_bf16(al0, fh[tj], acc[tj], 0, 0, 0);
            acc[tj]     = __builtin_amdgcn_mfma_f32_16x16x32_bf16(ah0, fl[tj], acc[tj], 0, 0, 0);
            acc[tj]     = __builtin_amdgcn_mfma_f32_16x16x32_bf16(ah0, fh[tj], acc[tj], 0, 0, 0);
            acc[8 + tj] = __builtin_amdgcn_mfma_f32_16x16x32_bf16(al1, fh[tj], acc[8 + tj], 0, 0, 0);
            acc[8 + tj] = __builtin_amdgcn_mfma_f32_16x16x32_bf16(ah1, fl[tj], acc[8 + tj], 0, 0, 0);
            acc[8 + tj] = __builtin_amdgcn_mfma_f32_16x16x32_bf16(ah1, fh[tj], acc[8 + tj], 0, 0, 0);
        }
    }

    // colsum(A): LDS combine then 8-way slotted global atomics
#pragma unroll
    for (int j = 0; j < 4; ++j) atomicAdd(&s_lds[(t & 31) * 4 + j], s_part[j]);
    __syncthreads();
    if (t < 128) atomicAdd(ws + WS_COLSA + (blockIdx.x & 7) * 128 + t, s_lds[t]);

    // G partial -> plain stores (disjoint per block)
    float* Gs = Gpart + (size_t)blockIdx.x * 16384;
#pragma unroll
    for (int a2 = 0; a2 < 2; ++a2) {
#pragma unroll
        for (int tj = 0; tj < 8; ++tj) {
#pragma unroll
            for (int g = 0; g < 4; ++g) {
                int gi = (2 * wave + a2) * 16 + lg * 4 + g;
                int gj = tj * 16 + lm;
                Gs[gi * 128 + gj] = acc[a2 * 8 + tj][g];
            }
        }
    }
}

// K1b: reduce GRAM_BLOCKS partials -> G final in ws
__global__ __launch_bounds__(256) void k1b_sumG(const float* __restrict__ Gpart,
                                                float* __restrict__ ws)
{
    int i = blockIdx.x * 256 + threadIdx.x;   // 0..16383
    float v = 0.f;
#pragma unroll 8
    for (int s = 0; s < GRAM_BLOCKS; ++s) v += Gpart[(size_t)s * 16384 + i];
    ws[WS_GF + i] = v;
}

// K2: per-column BN stats from Gram: mean = (colsum(A).w)/N, sumsq = w^T G w.
__global__ __launch_bounds__(128) void k2_finalize(
    const float* __restrict__ W, const float* __restrict__ gamma,
    const float* __restrict__ beta, float* __restrict__ ws, int Brows)
{
    __shared__ float wcol[128];
    __shared__ float red[4];
    const int t = threadIdx.x, n = blockIdx.x;
    wcol[t] = W[(size_t)t * UNITS + n];
    __syncthreads();
    const float* GF = ws + WS_GF;
    float q = 0.f;
#pragma unroll 8
    for (int i = 0; i < 128; ++i) q += GF[i * 128 + t] * wcol[i];   // symmetric G
    q *= wcol[t];
    float csa = 0.f;
#pragma unroll
    for (int sl = 0; sl < 8; ++sl) csa += ws[WS_COLSA + sl * 128 + t];
    float mp = csa * wcol[t];
#pragma unroll
    for (int off = 32; off; off >>= 1) {
        q  += __shfl_xor(q, off, 64);
        mp += __shfl_xor(mp, off, 64);
    }
    if ((t & 63) == 0) { red[(t >> 6) * 2] = q; red[(t >> 6) * 2 + 1] = mp; }
    __syncthreads();
    if (t == 0) {
        float sumsq = red[0] + red[2], ssum = red[1] + red[3];
        float invB = 1.0f / (float)Brows;
        float mean = ssum * invB;
        float var  = sumsq * invB - mean * mean;
        float rstd = rsqrtf(var + 1e-3f);
        float sc   = rstd * gamma[n];
        ws[WS_SCALE + n] = sc;
        ws[WS_SHIFT + n] = beta[n] - mean * sc;
    }
}

// K3: fused GEMM (split-bf16 MFMA) + BN + block-level Newton sparsemax +
// mask write + entropy. Block = 512 thr = 2 row-stripes x 4 col-waves; 32 rows.
// (Round-4 structure: LDS 2 KB, occupancy-friendly.)
__global__ __launch_bounds__(512, 4) void k3_fused(
    const float* __restrict__ A, const unsigned short* __restrict__ Whi,
    const unsigned short* __restrict__ Wlo, const float* __restrict__ prior,
    float* __restrict__ out, float* __restrict__ ws)
{
    __shared__ float lds_m[8][16];
    __shared__ float lds_S[8][16];
    __shared__ float lds_K[8][16];
    __shared__ float lds_e[8];
    __shared__ int s_flag[2];

    const int tid = threadIdx.x;
    const int wave = tid >> 6, lane = tid & 63, lg = lane >> 4, lm = lane & 15;
    const int rs = wave >> 2;          // row stripe 0/1
    const int cw = wave & 3;           // col wave: cols [cw*128, +128)
    const int r0 = blockIdx.x * 32 + rs * 16;

    // A fragments (16 rows, full K=128), truncation hi/lo split
    short8 ahi[4], alo[4];
    const float* arow = A + (size_t)(r0 + lm) * DIN + lg * 8;
#pragma unroll
    for (int c = 0; c < 4; ++c) {
        float4 f0 = *(const float4*)(arow + c * 32);
        float4 f1 = *(const float4*)(arow + c * 32 + 4);
        float fv[8] = {f0.x, f0.y, f0.z, f0.w, f1.x, f1.y, f1.z, f1.w};
#pragma unroll
        for (int j = 0; j < 8; ++j) {
            unsigned uv = __float_as_uint(fv[j]);
            float lo = fv[j] - __uint_as_float(uv & 0xFFFF0000u);
            ahi[c][j] = (short)(uv >> 16);
            alo[c][j] = (short)(__float_as_uint(lo) >> 16);
        }
    }

    f32x4 acc[8];
#pragma unroll
    for (int i = 0; i < 8; ++i) acc[i] = (f32x4){0.f, 0.f, 0.f, 0.f};

#pragma unroll
    for (int c = 0; c < 4; ++c) {
        const short8* bh = (const short8*)Whi + (c * 32 + cw * 8) * 64 + lane;
        const short8* bl = (const short8*)Wlo + (c * 32 + cw * 8) * 64 + lane;
#pragma unroll
        for (int t8 = 0; t8 < 8; ++t8) {
            short8 h = bh[t8 * 64];
            short8 l = bl[t8 * 64];
            acc[t8] = __builtin_amdgcn_mfma_f32_16x16x32_bf16(alo[c], h, acc[t8], 0, 0, 0);
            acc[t8] = __builtin_amdgcn_mfma_f32_16x16x32_bf16(ahi[c], l, acc[t8], 0, 0, 0);
            acc[t8] = __builtin_amdgcn_mfma_f32_16x16x32_bf16(ahi[c], h, acc[t8], 0, 0, 0);
        }
    }

    // BN scale/shift for my cols
    float sc[8], sh[8];
#pragma unroll
    for (int t8 = 0; t8 < 8; ++t8) {
        int col = cw * 128 + t8 * 16 + lm;
        sc[t8] = ws[WS_SCALE + col];
        sh[t8] = ws[WS_SHIFT + col];
    }

    // z = prior * (x*sc + sh), in place in acc
    const float* prow = prior + (size_t)(r0 + lg * 4) * UNITS + cw * 128 + lm;
#pragma unroll
    for (int t8 = 0; t8 < 8; ++t8) {
#pragma unroll
        for (int g = 0; g < 4; ++g) {
            float p = prow[(size_t)g * UNITS + t8 * 16];
            acc[t8][g] = p * fmaf(acc[t8][g], sc[t8], sh[t8]);
        }
    }

    // per-row max: in-lane over t8, then 16-lane group reduce, then cross-wave
    f32x4 mx = acc[0];
#pragma unroll
    for (int t8 = 1; t8 < 8; ++t8) {
#pragma unroll
        for (int g = 0; g < 4; ++g) mx[g] = fmaxf(mx[g], acc[t8][g]);
    }
#pragma unroll
    for (int off = 1; off <= 8; off <<= 1) {
#pragma unroll
        for (int g = 0; g < 4; ++g) mx[g] = fmaxf(mx[g], __shfl_xor(mx[g], off, 64));
    }
    if (lm == 0) {
#pragma unroll
        for (int g = 0; g < 4; ++g) lds_m[wave][lg * 4 + g] = mx[g];
    }
    if (tid == 0) s_flag[0] = 0;
    __syncthreads();

    float tau[4];
#pragma unroll
    for (int g = 0; g < 4; ++g) {
        int rr = lg * 4 + g;
        float m0 = fmaxf(fmaxf(lds_m[rs * 4 + 0][rr], lds_m[rs * 4 + 1][rr]),
                         fmaxf(lds_m[rs * 4 + 2][rr], lds_m[rs * 4 + 3][rr]));
        tau[g] = m0 - 1.0f;
    }

    // Newton on f(tau)=sum(relu(z-tau))-1: tau monotone increasing, exact
    // fixed point in ~4-6 iters; block-uniform early exit via LDS flag.
    for (int it = 0; it < 24; ++it) {
        float S[4] = {0.f, 0.f, 0.f, 0.f}, K[4] = {0.f, 0.f, 0.f, 0.f};
#pragma unroll
        for (int t8 = 0; t8 < 8; ++t8) {
#pragma unroll
            for (int g = 0; g < 4; ++g) {
                float v = acc[t8][g];
                if (v > tau[g]) { S[g] += v; K[g] += 1.f; }
            }
        }
#pragma unroll
        for (int off = 1; off <= 8; off <<= 1) {
#pragma unroll
            for (int g = 0; g < 4; ++g) {
                S[g] += __shfl_xor(S[g], off, 64);
                K[g] += __shfl_xor(K[g], off, 64);
            }
        }
        if (tid == 0) s_flag[(it + 1) & 1] = 0;   // prepare next iter's flag
        if (lm == 0) {
#pragma unroll
            for (int g = 0; g < 4; ++g) {
                lds_S[wave][lg * 4 + g] = S[g];
                lds_K[wave][lg * 4 + g] = K[g];
            }
        }
        __syncthreads();
        int changed = 0;
#pragma unroll
        for (int g = 0; g < 4; ++g) {
            int rr = lg * 4 + g;
            float St = lds_S[rs * 4 + 0][rr] + lds_S[rs * 4 + 1][rr] +
                       lds_S[rs * 4 + 2][rr] + lds_S[rs * 4 + 3][rr];
            float Kt = lds_K[rs * 4 + 0][rr] + lds_K[rs * 4 + 1][rr] +
                       lds_K[rs * 4 + 2][rr] + lds_K[rs * 4 + 3][rr];
            float nt = (St - 1.0f) / Kt;
            if (nt > tau[g]) { tau[g] = nt; changed = 1; }
        }
        if (changed) s_flag[it & 1] = 1;
        __syncthreads();
        if (!s_flag[it & 1]) break;
    }

    // mask + entropy + store
    float e = 0.f;
    float* orow = out + (size_t)(r0 + lg * 4) * UNITS + cw * 128 + lm;
#pragma unroll
    for (int t8 = 0; t8 < 8; ++t8) {
#pragma unroll
        for (int g = 0; g < 4; ++g) {
            float v = fmaxf(acc[t8][g] - tau[g], 0.f);
            orow[(size_t)g * UNITS + t8 * 16] = v;
            e -= v * __logf(v + 1e-15f);
        }
    }
#pragma unroll
    for (int off = 32; off; off >>= 1) e += __shfl_xor(e, off, 64);
    if (lane == 0) lds_e[wave] = e;
    __syncthreads();
    if (tid == 0) {
        float tot = 0.f;
#pragma unroll
        for (int w = 0; w < 8; ++w) tot += lds_e[w];
        atomicAdd(&ws[WS_ESLOT + (blockIdx.x & (N_ESLOT - 1))], tot);
    }
}

// K4: reduce entropy slots -> scalar loss
__global__ void k4_loss(const float* __restrict__ ws, float* __restrict__ out_loss,
                        int Brows)
{
    __shared__ float sh[512];
    int t = threadIdx.x;
    sh[t] = ws[WS_ESLOT + t];
    __syncthreads();
    for (int s = 256; s > 0; s >>= 1) {
        if (t < s) sh[t] += sh[t + s];
        __syncthreads();
    }
    if (t == 0) out_loss[0] = 1e-3f * (sh[0] / (float)Brows) * (1.0f / 3.0f);
}

extern "C" void kernel_launch(void* const* d_in, const int* in_sizes, int n_in,
                              void* d_out, int out_size, void* d_ws, size_t ws_size,
                              hipStream_t stream)
{
    const float* inputs = (const float*)d_in[0];
    const float* prior  = (const float*)d_in[1];
    const float* Wm     = (const float*)d_in[2];
    const float* gamma  = (const float*)d_in[3];
    const float* beta   = (const float*)d_in[4];
    float* out = (float*)d_out;
    float* ws  = (float*)d_ws;
    unsigned short* Whi = (unsigned short*)(ws + WS_WHI);
    unsigned short* Wlo = (unsigned short*)(ws + WS_WLO);
    const int Brows = in_sizes[1] / UNITS;   // 131072

    // d_out doubles as Gram-partial scratch (33.5 MB) before k3 overwrites it.
    float* Gpart = out;

    hipMemsetAsync(ws, 0, WS_ZERO_FLOATS * sizeof(float), stream);

    k0_packW<<<256, 256, 0, stream>>>(Wm, Whi, Wlo);
    k1a_gram<<<GRAM_BLOCKS, 256, 0, stream>>>(inputs, Gpart, ws, Brows);
    k1b_sumG<<<64, 256, 0, stream>>>(Gpart, ws);
    k2_finalize<<<UNITS, 128, 0, stream>>>(Wm, gamma, beta, ws, Brows);
    k3_fused<<<Brows / 32, 512, 0, stream>>>(inputs, Whi, Wlo, prior, out, ws);
    k4_loss<<<1, N_ESLOT, 0, stream>>>(ws, out + (size_t)Brows * UNITS, Brows);
}